// Round 1
// baseline (1093.634 us; speedup 1.0000x reference)
//
#include <hip/hip_runtime.h>

#define DD 25088      // C*Hp*Wp = 512*49
#define HH 4096
#define NCOMB 25      // 21 classes + 4 reg
#define NCLS 21
#define NBOX 512
#define BATCH 4
#define BN 2048       // BATCH*NBOX

// workspace layout in floats
#define WSMT_OFF   0        // [4096][28] padded transpose of [Wc;Wr]
#define BIAS_OFF   114688   // [32]
#define WCOMB_OFF  114720   // [25][25088]  (byte off 458880, 16B aligned)
#define SCORES_OFF 741920   // [2048]
#define BOXES_OFF  743968   // [2048][4]    (byte off 2975872, 16B aligned)

__global__ __launch_bounds__(256) void k_transpose(const float* __restrict__ Wc,
                                                   const float* __restrict__ Wr,
                                                   float* __restrict__ Wsmt) {
    int idx = blockIdx.x * 256 + threadIdx.x;   // 4096*28 = 114688 exact
    int h = idx / 28, c = idx % 28;
    float v = 0.f;
    if (c < NCLS) v = Wc[(size_t)c * HH + h];
    else if (c < NCOMB) v = Wr[(size_t)(c - NCLS) * HH + h];
    Wsmt[idx] = v;
}

__global__ __launch_bounds__(256) void k_bias(const float* __restrict__ Wc,
                                              const float* __restrict__ bc,
                                              const float* __restrict__ Wr,
                                              const float* __restrict__ br,
                                              const float* __restrict__ b1,
                                              float* __restrict__ biasc) {
    __shared__ float red[256];
    int c = blockIdx.x, t = threadIdx.x;
    const float* wrow = (c < NCLS) ? (Wc + (size_t)c * HH) : (Wr + (size_t)(c - NCLS) * HH);
    float s = 0.f;
    for (int h = t; h < HH; h += 256) s += wrow[h] * b1[h];
    red[t] = s; __syncthreads();
    for (int o = 128; o; o >>= 1) { if (t < o) red[t] += red[t + o]; __syncthreads(); }
    if (t == 0) biasc[c] = red[0] + ((c < NCLS) ? bc[c] : br[c - NCLS]);
}

// Wcomb[c][d] += sum_h Wsmt[h][c] * W1[h][d]  over this block's 512-h chunk.
__global__ __launch_bounds__(256) void k_gemm1(const float* __restrict__ W1,
                                               const float* __restrict__ Wsmt,
                                               float* __restrict__ Wcomb) {
    int d  = blockIdx.x * 256 + threadIdx.x;    // 98*256 = 25088 exact
    int h0 = blockIdx.y * 512;                  // 8 chunks
    const float*  w1p = W1 + (size_t)h0 * DD + d;
    const float4* wst = (const float4*)(Wsmt + (size_t)h0 * 28);
    float acc[NCOMB];
#pragma unroll
    for (int c = 0; c < NCOMB; ++c) acc[c] = 0.f;
#pragma unroll 4
    for (int hh = 0; hh < 512; ++hh) {
        float w = w1p[(size_t)hh * DD];
        float4 a0 = wst[hh * 7 + 0], a1 = wst[hh * 7 + 1], a2 = wst[hh * 7 + 2],
               a3 = wst[hh * 7 + 3], a4 = wst[hh * 7 + 4], a5 = wst[hh * 7 + 5],
               a6 = wst[hh * 7 + 6];
        acc[0]  += a0.x * w; acc[1]  += a0.y * w; acc[2]  += a0.z * w; acc[3]  += a0.w * w;
        acc[4]  += a1.x * w; acc[5]  += a1.y * w; acc[6]  += a1.z * w; acc[7]  += a1.w * w;
        acc[8]  += a2.x * w; acc[9]  += a2.y * w; acc[10] += a2.z * w; acc[11] += a2.w * w;
        acc[12] += a3.x * w; acc[13] += a3.y * w; acc[14] += a3.z * w; acc[15] += a3.w * w;
        acc[16] += a4.x * w; acc[17] += a4.y * w; acc[18] += a4.z * w; acc[19] += a4.w * w;
        acc[20] += a5.x * w; acc[21] += a5.y * w; acc[22] += a5.z * w; acc[23] += a5.w * w;
        acc[24] += a6.x * w;
    }
#pragma unroll
    for (int c = 0; c < NCOMB; ++c) atomicAdd(&Wcomb[(size_t)c * DD + d], acc[c]);
}

// One wave per ROI row: dot(feats_row, Wcomb[c]) for c=0..24, then fused
// softmax / argmax / validity / box decode on lane 0.
__global__ __launch_bounds__(512) void k_head(const float* __restrict__ rois,
                                              const float* __restrict__ proposals,
                                              const float* __restrict__ Wcomb,
                                              const float* __restrict__ biasc,
                                              float* __restrict__ scores,
                                              float* __restrict__ boxes) {
    int wv = threadIdx.x >> 6, lane = threadIdx.x & 63;
    int row = blockIdx.x * 8 + wv;              // 256*8 = 2048 exact
    const float4* f = (const float4*)(rois + (size_t)row * DD);
    float acc[NCOMB];
#pragma unroll
    for (int c = 0; c < NCOMB; ++c) acc[c] = 0.f;
    for (int k = 0; k < 98; ++k) {              // 6272 quads / 64 lanes
        int q = k * 64 + lane;
        float4 fv = f[q];
#pragma unroll
        for (int c = 0; c < NCOMB; ++c) {
            float4 w4 = ((const float4*)(Wcomb + (size_t)c * DD))[q];
            acc[c] += fv.x * w4.x + fv.y * w4.y + fv.z * w4.z + fv.w * w4.w;
        }
    }
#pragma unroll
    for (int c = 0; c < NCOMB; ++c) {
        float s = acc[c];
#pragma unroll
        for (int o = 32; o; o >>= 1) s += __shfl_down(s, o);
        acc[c] = s;
    }
    if (lane == 0) {
        float logit[NCLS];
        float m = -1e30f; int idx = 0;
#pragma unroll
        for (int c = 0; c < NCLS; ++c) {
            logit[c] = acc[c] + biasc[c];
            if (logit[c] > m) { m = logit[c]; idx = c; }
        }
        float sum = 0.f;
#pragma unroll
        for (int c = 0; c < NCLS; ++c) sum += expf(logit[c] - m);
        float score = 1.f / sum;                 // exp(max-m)/sum with m==max
        float r0 = acc[21] + biasc[21], r1 = acc[22] + biasc[22];
        float r2 = acc[23] + biasc[23], r3 = acc[24] + biasc[24];
        bool valid = (idx != 0) && (score >= 0.01f);
        float4 p = ((const float4*)proposals)[row];
        float px = p.x + p.z * r0, py = p.y + p.w * r1;
        float pw = p.z * expf(r2), ph = p.w * expf(r3);
        scores[row] = valid ? score : 0.f;
        ((float4*)boxes)[row] = make_float4(px, py, pw, ph);
    }
}

// One block per batch image: stable rank-sort, ballot IoU bitmask,
// single-wave greedy scan, fused output write.
__global__ __launch_bounds__(512) void k_nms(const float* __restrict__ scores,
                                             const float* __restrict__ boxes,
                                             float* __restrict__ out) {
    __shared__ float un_sc[NBOX];
    __shared__ float sx0[NBOX], sy0[NBOX], sx1[NBOX], sy1[NBOX], sar[NBOX], ssc[NBOX];
    __shared__ int   sord[NBOX], svalid[NBOX];
    __shared__ unsigned long long smask[NBOX][8];
    __shared__ unsigned long long ssup[8];

    int b = blockIdx.x, t = threadIdx.x;
    int n = t;
    float sc = scores[b * NBOX + n];
    float4 bx = ((const float4*)boxes)[b * NBOX + n];
    float x0 = fminf(fmaxf(bx.x, 0.f), 599.f);
    float y0 = fminf(fmaxf(bx.y, 0.f), 599.f);
    float x1 = fminf(fmaxf(bx.x + bx.z - 1.f, 0.f), 599.f);
    float y1 = fminf(fmaxf(bx.y + bx.w - 1.f, 0.f), 599.f);
    un_sc[n] = sc;
    __syncthreads();
    // stable rank = #{j : s_j > s_n or (s_j == s_n and j < n)}
    int r = 0;
    for (int j = 0; j < NBOX; ++j) {
        float sj = un_sc[j];
        r += (sj > sc) || (sj == sc && j < n);
    }
    sx0[r] = x0; sy0[r] = y0; sx1[r] = x1; sy1[r] = y1;
    sar[r] = fmaxf(x1 - x0 + 1.f, 0.f) * fmaxf(y1 - y0 + 1.f, 0.f);
    ssc[r] = sc; sord[r] = n; svalid[r] = (sc > 0.f) ? 1 : 0;
    __syncthreads();

    int wv = t >> 6, lane = t & 63;
    for (int ii = 0; ii < 64; ++ii) {
        int i = ii * 8 + wv;                    // 8 waves cover 512 rows
        float ix0 = sx0[i], iy0 = sy0[i], ix1 = sx1[i], iy1 = sy1[i], ia = sar[i];
#pragma unroll
        for (int g = 0; g < 8; ++g) {
            int j = g * 64 + lane;
            float xx0 = fmaxf(ix0, sx0[j]), yy0 = fmaxf(iy0, sy0[j]);
            float xx1 = fminf(ix1, sx1[j]), yy1 = fminf(iy1, sy1[j]);
            float inter = fmaxf(xx1 - xx0 + 1.f, 0.f) * fmaxf(yy1 - yy0 + 1.f, 0.f);
            float iou = inter / (ia + sar[j] - inter + 1e-9f);
            bool okb = (j != i) && (iou > 0.5f);
            unsigned long long mres = __ballot(okb);
            if (lane == 0) smask[i][g] = mres;
        }
    }
    __syncthreads();

    if (t < 64) {                               // single-wave greedy scan
        unsigned long long sup = 0ull;
        for (int i = 0; i < NBOX; ++i) {
            unsigned long long sw = __shfl(sup, i >> 6);
            bool dead = (sw >> (i & 63)) & 1ull;
            if (!dead && svalid[i]) {
                if (lane < 8) sup |= smask[i][lane];
            }
        }
        if (lane < 8) ssup[lane] = sup;
    }
    __syncthreads();

    int rr = t;
    bool keep = !((ssup[rr >> 6] >> (rr & 63)) & 1ull) && svalid[rr];
    int nn = sord[rr];
    out[b * NBOX + nn] = keep ? ssc[rr] : 0.f;
    float4 bxn = ((const float4*)boxes)[b * NBOX + nn];
    float kx = keep ? bxn.x : 0.f, ky = keep ? bxn.y : 0.f;
    float kw = keep ? bxn.z : 0.f, kh = keep ? bxn.w : 0.f;
    ((float4*)(out + BN + (size_t)(b * NBOX + nn) * 4))[0] =
        make_float4(kx, ky, kx + kw - 1.f, ky + kh - 1.f);
}

extern "C" void kernel_launch(void* const* d_in, const int* in_sizes, int n_in,
                              void* d_out, int out_size, void* d_ws, size_t ws_size,
                              hipStream_t stream) {
    (void)in_sizes; (void)n_in; (void)out_size; (void)ws_size;
    const float* rois      = (const float*)d_in[0];
    const float* proposals = (const float*)d_in[1];
    const float* W1        = (const float*)d_in[2];
    const float* b1        = (const float*)d_in[3];
    const float* Wc        = (const float*)d_in[4];
    const float* bc        = (const float*)d_in[5];
    const float* Wr        = (const float*)d_in[6];
    const float* br        = (const float*)d_in[7];
    float* out = (float*)d_out;
    float* ws  = (float*)d_ws;
    float* Wsmt   = ws + WSMT_OFF;
    float* biasc  = ws + BIAS_OFF;
    float* Wcomb  = ws + WCOMB_OFF;
    float* scores = ws + SCORES_OFF;
    float* boxes  = ws + BOXES_OFF;

    hipMemsetAsync(Wcomb, 0, (size_t)NCOMB * DD * sizeof(float), stream);
    k_transpose<<<448, 256, 0, stream>>>(Wc, Wr, Wsmt);
    k_bias<<<NCOMB, 256, 0, stream>>>(Wc, bc, Wr, br, b1, biasc);
    k_gemm1<<<dim3(98, 8), 256, 0, stream>>>(W1, Wsmt, Wcomb);
    k_head<<<256, 512, 0, stream>>>(rois, proposals, Wcomb, biasc, scores, boxes);
    k_nms<<<BATCH, 512, 0, stream>>>(scores, boxes, out);
}